// Round 15
// baseline (65.927 us; speedup 1.0000x reference)
//
#include <hip/hip_runtime.h>
#include <math.h>

#define GG 2000   // num_graphs (reference constant)

typedef short bf16x8 __attribute__((ext_vector_type(8)));
typedef float f32x4  __attribute__((ext_vector_type(4)));

__device__ __forceinline__ unsigned short f2b(float f) {
    unsigned int u = __float_as_uint(f);
    u += 0x7FFFu + ((u >> 16) & 1u);          // round-to-nearest-even
    return (unsigned short)(u >> 16);
}
__device__ __forceinline__ unsigned short f2b_up(float f) {   // round-half-up, 2 instr
    return (unsigned short)((__float_as_uint(f) + 0x8000u) >> 16);
}

// ---------------- Phase A: scores = tanh(x@w1^T)@w2^T ----------------
// r10/r13 structure: 512-thr blocks (8 waves), 64-node tiles, nt-split wave
// pairs, 3 barriers/tile, 24 waves/CU. T14-lite: next tile's global loads are
// issued after barrier A (latency drains under tanh+GEMM2+merge); convert+write
// stays after barrier B. pre[] liveness avoids GEMM1's register-pressure peak.
__global__ __launch_bounds__(512, 6) void score_kernel(
    const float* __restrict__ x, const float* __restrict__ w1,
    const float* __restrict__ w2, float* __restrict__ scores,
    int n_nodes, int ntile)
{
    __shared__ __align__(16) unsigned short w1b[16384];  // [128 hid][128 k] bf16, slot^=(row&7)
    __shared__ __align__(16) unsigned short xb[8192];    // [64 n][128 k] bf16; per-wave h aliases (2KB/wave)
    __shared__ __align__(16) f32x4 pb[4][64];            // GEMM2 partials from half=1 waves

    const int t = threadIdx.x;      // 0..511
    const int lane = t & 63;
    const int w = t >> 6;           // 0..7
    const int l15 = lane & 15;
    const int lg  = lane >> 4;
    const int grp  = w & 3;         // row group
    const int half = w >> 2;        // hidden half

    // ---- stage w1 -> bf16 LDS (8 f4/thread) ----
#pragma unroll
    for (int i = 0; i < 8; ++i) {
        int f4 = i * 512 + t;                  // 4096 float4
        int row = f4 >> 5, q = f4 & 31;
        float4 v = ((const float4*)w1)[f4];
        ushort4 p;
        p.x = f2b(v.x); p.y = f2b(v.y); p.z = f2b(v.z); p.w = f2b(v.w);
        int slot = (q >> 1) ^ (row & 7);
        *(ushort4*)((char*)w1b + row * 256 + slot * 16 + (q & 1) * 8) = p;
    }
    // ---- w2 b-frags for this wave's 2 local ks (col o = l15; rows 8..15 zero) ----
    bf16x8 w2f[2];
#pragma unroll
    for (int kk = 0; kk < 2; ++kk) {
        int ks = half * 2 + kk;
        float tmp[8];
        if (l15 < 8) {
            float4 u0 = ((const float4*)w2)[l15 * 32 + ks * 8 + lg * 2];
            float4 u1 = ((const float4*)w2)[l15 * 32 + ks * 8 + lg * 2 + 1];
            tmp[0]=u0.x; tmp[1]=u0.y; tmp[2]=u0.z; tmp[3]=u0.w;
            tmp[4]=u1.x; tmp[5]=u1.y; tmp[6]=u1.z; tmp[7]=u1.w;
        } else {
#pragma unroll
            for (int i = 0; i < 8; ++i) tmp[i] = 0.f;
        }
        bf16x8 r;
#pragma unroll
        for (int i = 0; i < 8; ++i) r[i] = (short)f2b(tmp[i]);
        w2f[kk] = r;
    }
    // ---- stage first x tile (4 f4/thread) ----
    int tile = blockIdx.x;
    if (tile < ntile) {
#pragma unroll
        for (int i = 0; i < 4; ++i) {
            int f4 = i * 512 + t;              // 2048 float4
            int row = f4 >> 5, q = f4 & 31;
            int node = tile * 64 + row; if (node >= n_nodes) node = n_nodes - 1;
            float4 v = ((const float4*)x)[(size_t)node * 32 + q];
            ushort4 p;
            p.x = f2b(v.x); p.y = f2b(v.y); p.z = f2b(v.z); p.w = f2b(v.w);
            int slot = (q >> 1) ^ (row & 7);
            *(ushort4*)((char*)xb + row * 256 + slot * 16 + (q & 1) * 8) = p;
        }
    }
    __syncthreads();   // w1b + first xb ready

    char* myhb = (char*)xb + w * 2048;   // wave-private h: [16 m][64 n'] bf16, 128B rows

    for (; tile < ntile; tile += gridDim.x) {
        const int base = tile * 64;
        const int nxt = tile + gridDim.x;
        // ---- GEMM1: rows grp*16..+15, global nt = half*4 + ntl ----
        f32x4 acc1[4];
#pragma unroll
        for (int ntl = 0; ntl < 4; ++ntl)
#pragma unroll
            for (int r = 0; r < 4; ++r) acc1[ntl][r] = 0.f;
#pragma unroll
        for (int ks = 0; ks < 4; ++ks) {
            int arow = grp * 16 + l15;
            int aslot = (ks * 4 + lg) ^ (arow & 7);
            bf16x8 af = *(const bf16x8*)((char*)xb + arow * 256 + aslot * 16);
#pragma unroll
            for (int ntl = 0; ntl < 4; ++ntl) {
                int brow = (half * 4 + ntl) * 16 + l15;
                int bslot = (ks * 4 + lg) ^ (brow & 7);
                bf16x8 bfr = *(bf16x8*)((char*)w1b + brow * 256 + bslot * 16);
                acc1[ntl] = __builtin_amdgcn_mfma_f32_16x16x32_bf16(af, bfr, acc1[ntl], 0, 0, 0);
            }
        }
        __syncthreads();   // A: all xb A-reads done before h overwrites xb
        // ---- T14-lite: issue next tile's loads now; latency drains under tanh+GEMM2 ----
        float4 pre[4];
        if (nxt < ntile) {
#pragma unroll
            for (int i = 0; i < 4; ++i) {
                int f4 = i * 512 + t;
                int row = f4 >> 5, q = f4 & 31;
                int node = nxt * 64 + row; if (node >= n_nodes) node = n_nodes - 1;
                pre[i] = ((const float4*)x)[(size_t)node * 32 + q];
            }
        }
        // ---- cheap tanh -> myhb: tanh(a) = 1 - 2*rcp(e^{2a}+1), saturation-safe ----
#pragma unroll
        for (int ntl = 0; ntl < 4; ++ntl)
#pragma unroll
            for (int r = 0; r < 4; ++r) {
                float aa = acc1[ntl][r];
                float e2 = __expf(2.f * aa);                       // inf for large aa: ok
                float th = fmaf(-2.f, __builtin_amdgcn_rcpf(e2 + 1.f), 1.f);
                int m = lg * 4 + r;
                int np = ntl * 16 + l15;
                int slot = ((np >> 3) + m) & 7;
                *(unsigned short*)(myhb + m * 128 + slot * 16 + (np & 7) * 2) = f2b_up(th);
            }
        // ---- GEMM2 (own k-half): A row m = l15, k-slot = kk*4+lg ----
        f32x4 acc2;
#pragma unroll
        for (int r = 0; r < 4; ++r) acc2[r] = 0.f;
#pragma unroll
        for (int kk = 0; kk < 2; ++kk) {
            int slot = ((kk * 4 + lg) + l15) & 7;
            bf16x8 hf = *(bf16x8*)(myhb + l15 * 128 + slot * 16);
            acc2 = __builtin_amdgcn_mfma_f32_16x16x32_bf16(hf, w2f[kk], acc2, 0, 0, 0);
        }
        if (half) pb[grp][lane] = acc2;
        __syncthreads();   // B: partials visible; all h reads done
        if (!half) {
            f32x4 po = pb[grp][lane];
#pragma unroll
            for (int r = 0; r < 4; ++r) acc2[r] += po[r];
            if (l15 < 8) {
#pragma unroll
                for (int r = 0; r < 4; ++r) {
                    int node = base + grp * 16 + lg * 4 + r;
                    if (node < n_nodes) scores[node * 8 + l15] = acc2[r];
                }
            }
        }
        // ---- T14 write-late: staged regs -> xb (h reads done at barrier B) ----
        if (nxt < ntile) {
#pragma unroll
            for (int i = 0; i < 4; ++i) {
                int f4 = i * 512 + t;
                int row = f4 >> 5, q = f4 & 31;
                ushort4 p;
                p.x = f2b(pre[i].x); p.y = f2b(pre[i].y); p.z = f2b(pre[i].z); p.w = f2b(pre[i].w);
                int slot = (q >> 1) ^ (row & 7);
                *(ushort4*)((char*)xb + row * 256 + slot * 16 + (q & 1) * 8) = p;
            }
        }
        __syncthreads();   // C: next xb ready
    }
}

// ---------------- Phase B+C: per-graph bounds (binary search) + stats (in-reg)
//                  + staged PV. One block per graph (r14, frozen). ----------------
__global__ __launch_bounds__(256) void out_kernel(
    const float* __restrict__ x, const float* __restrict__ scores,
    const int* __restrict__ batch, float* __restrict__ out, int n_nodes)
{
    __shared__ float redm[256], redl[256];
    __shared__ __align__(16) float xsl[16 * 128];
    __shared__ __align__(16) float atl[16 * 8];
    __shared__ int sse[2];
    const int g = blockIdx.x, t = threadIdx.x;
    const int lane = t & 63;

    // ---- segment bounds: lower_bound(batch, g) and (batch, g+1) ----
    if (t < 2) {
        int v = g + t;
        int lo = 0, hi = n_nodes;
        while (lo < hi) { int mid = (lo + hi) >> 1; if (batch[mid] < v) lo = mid + 1; else hi = mid; }
        sse[t] = lo;
    }
    __syncthreads();
    const int s = sse[0];
    const int e = sse[1];
    float* og = out + (size_t)g * 1024;
    const int f = t & 127, ob = t >> 7;
    if (e <= s) {     // empty graph: segment_sum identity = 0 (block-uniform exit)
        og[ob * 512 + f] = 0.f; og[ob * 512 + 128 + f] = 0.f;
        og[ob * 512 + 256 + f] = 0.f; og[ob * 512 + 384 + f] = 0.f;
        return;
    }
    const int o = t & 7, j0 = t >> 3;

    // ---- pass 1: graph max per head (shfl-reduced; every thread gets M for o=t&7) ----
    float m = -INFINITY;
    for (int n = s + j0; n < e; n += 32) m = fmaxf(m, scores[n * 8 + o]);
    redm[t] = m;
    __syncthreads();
    float M = fmaxf(fmaxf(redm[lane], redm[lane + 64]), fmaxf(redm[lane + 128], redm[lane + 192]));
    M = fmaxf(M, __shfl_xor(M, 8));
    M = fmaxf(M, __shfl_xor(M, 16));
    M = fmaxf(M, __shfl_xor(M, 32));
    // ---- pass 2: denom per head ----
    float l = 0.f;
    for (int n = s + j0; n < e; n += 32) l += __expf(scores[n * 8 + o] - M);
    redl[t] = l;
    __syncthreads();
    float L = (redl[lane] + redl[lane + 64]) + (redl[lane + 128] + redl[lane + 192]);
    L += __shfl_xor(L, 8);
    L += __shfl_xor(L, 16);
    L += __shfl_xor(L, 32);
    const float gi = 1.f / L;

    // ---- PV: 16-node chunks, xsl + atl staged ----
    float a0 = 0.f, a1 = 0.f, a2 = 0.f, a3 = 0.f;
    for (int c = s; c < e; c += 16) {
        const int cnt = min(16, e - c);
        __syncthreads();   // protects prev-iter reads (first iter: redm/redl done)
#pragma unroll
        for (int i = 0; i < 2; ++i) {
            int f4 = i * 256 + t;
            int row = f4 >> 5, col4 = f4 & 31;
            if (row < cnt)
                ((float4*)xsl)[row * 32 + col4] = ((const float4*)x)[(size_t)(c + row) * 32 + col4];
        }
        if (t < 128) {
            int j = t >> 3;
            if (j < cnt)
                atl[j * 8 + o] = __expf(scores[(c + j) * 8 + o] - M) * gi;
        }
        __syncthreads();
        for (int j = 0; j < cnt; ++j) {
            float xv = xsl[j * 128 + f];
            float4 a4 = ((const float4*)atl)[j * 2 + ob];
            a0 = fmaf(a4.x, xv, a0); a1 = fmaf(a4.y, xv, a1);
            a2 = fmaf(a4.z, xv, a2); a3 = fmaf(a4.w, xv, a3);
        }
    }
    const int gb = ob * 512 + f;
    og[gb]       = a0;
    og[gb + 128] = a1;
    og[gb + 256] = a2;
    og[gb + 384] = a3;
}

extern "C" void kernel_launch(void* const* d_in, const int* in_sizes, int n_in,
                              void* d_out, int out_size, void* d_ws, size_t ws_size,
                              hipStream_t stream)
{
    const float* x     = (const float*)d_in[0];
    const int*   batch = (const int*)d_in[1];
    const float* w1    = (const float*)d_in[2];
    const float* w2    = (const float*)d_in[3];
    const int n_nodes  = in_sizes[1];
    float* out = (float*)d_out;

    float* scores = (float*)d_ws;   // n*8 floats

    const int ntile = (n_nodes + 63) / 64;
    hipLaunchKernelGGL(score_kernel, dim3(768), dim3(512), 0, stream, x, w1, w2, scores, n_nodes, ntile);
    hipLaunchKernelGGL(out_kernel,   dim3(GG),  dim3(256), 0, stream, x, scores, batch, out, n_nodes);
}

// Round 16
// 57.203 us; speedup vs baseline: 1.1525x; 1.1525x over previous
//
#include <hip/hip_runtime.h>
#include <math.h>

#define GG 2000   // num_graphs (reference constant)

typedef short bf16x8 __attribute__((ext_vector_type(8)));
typedef float f32x4  __attribute__((ext_vector_type(4)));

__device__ __forceinline__ unsigned short f2b(float f) {
    unsigned int u = __float_as_uint(f);
    u += 0x7FFFu + ((u >> 16) & 1u);          // round-to-nearest-even
    return (unsigned short)(u >> 16);
}
__device__ __forceinline__ unsigned short f2b_up(float f) {   // round-half-up, 2 instr
    return (unsigned short)((__float_as_uint(f) + 0x8000u) >> 16);
}

// ---------------- Phase A: scores = tanh(x@w1^T)@w2^T ----------------
// r10/r13 structure (frozen): 512-thr blocks (8 waves), 64-node tiles, nt-split
// wave pairs (grp = rows, half = hidden half), 3 barriers/tile, 24 waves/CU.
// NOTE: (512,6) => 85-VGPR cap. Falsified under this cap: reg-preload of next
// tile (r11/r15), atomic ticket queue (r12). Do not re-add without raising
// occupancy headroom first.
__global__ __launch_bounds__(512, 6) void score_kernel(
    const float* __restrict__ x, const float* __restrict__ w1,
    const float* __restrict__ w2, float* __restrict__ scores,
    int n_nodes, int ntile)
{
    __shared__ __align__(16) unsigned short w1b[16384];  // [128 hid][128 k] bf16, slot^=(row&7)
    __shared__ __align__(16) unsigned short xb[8192];    // [64 n][128 k] bf16; per-wave h aliases (2KB/wave)
    __shared__ __align__(16) f32x4 pb[4][64];            // GEMM2 partials from half=1 waves

    const int t = threadIdx.x;      // 0..511
    const int lane = t & 63;
    const int w = t >> 6;           // 0..7
    const int l15 = lane & 15;
    const int lg  = lane >> 4;
    const int grp  = w & 3;         // row group
    const int half = w >> 2;        // hidden half

    // ---- stage w1 -> bf16 LDS (8 f4/thread) ----
#pragma unroll
    for (int i = 0; i < 8; ++i) {
        int f4 = i * 512 + t;                  // 4096 float4
        int row = f4 >> 5, q = f4 & 31;
        float4 v = ((const float4*)w1)[f4];
        ushort4 p;
        p.x = f2b(v.x); p.y = f2b(v.y); p.z = f2b(v.z); p.w = f2b(v.w);
        int slot = (q >> 1) ^ (row & 7);
        *(ushort4*)((char*)w1b + row * 256 + slot * 16 + (q & 1) * 8) = p;
    }
    // ---- w2 b-frags for this wave's 2 local ks (col o = l15; rows 8..15 zero) ----
    bf16x8 w2f[2];
#pragma unroll
    for (int kk = 0; kk < 2; ++kk) {
        int ks = half * 2 + kk;
        float tmp[8];
        if (l15 < 8) {
            float4 u0 = ((const float4*)w2)[l15 * 32 + ks * 8 + lg * 2];
            float4 u1 = ((const float4*)w2)[l15 * 32 + ks * 8 + lg * 2 + 1];
            tmp[0]=u0.x; tmp[1]=u0.y; tmp[2]=u0.z; tmp[3]=u0.w;
            tmp[4]=u1.x; tmp[5]=u1.y; tmp[6]=u1.z; tmp[7]=u1.w;
        } else {
#pragma unroll
            for (int i = 0; i < 8; ++i) tmp[i] = 0.f;
        }
        bf16x8 r;
#pragma unroll
        for (int i = 0; i < 8; ++i) r[i] = (short)f2b(tmp[i]);
        w2f[kk] = r;
    }
    // ---- stage first x tile (4 f4/thread) ----
    int tile = blockIdx.x;
    if (tile < ntile) {
#pragma unroll
        for (int i = 0; i < 4; ++i) {
            int f4 = i * 512 + t;              // 2048 float4
            int row = f4 >> 5, q = f4 & 31;
            int node = tile * 64 + row; if (node >= n_nodes) node = n_nodes - 1;
            float4 v = ((const float4*)x)[(size_t)node * 32 + q];
            ushort4 p;
            p.x = f2b(v.x); p.y = f2b(v.y); p.z = f2b(v.z); p.w = f2b(v.w);
            int slot = (q >> 1) ^ (row & 7);
            *(ushort4*)((char*)xb + row * 256 + slot * 16 + (q & 1) * 8) = p;
        }
    }
    __syncthreads();   // w1b + first xb ready

    char* myhb = (char*)xb + w * 2048;   // wave-private h: [16 m][64 n'] bf16, 128B rows

    for (; tile < ntile; tile += gridDim.x) {
        const int base = tile * 64;
        // ---- GEMM1: rows grp*16..+15, global nt = half*4 + ntl ----
        f32x4 acc1[4];
#pragma unroll
        for (int ntl = 0; ntl < 4; ++ntl)
#pragma unroll
            for (int r = 0; r < 4; ++r) acc1[ntl][r] = 0.f;
#pragma unroll
        for (int ks = 0; ks < 4; ++ks) {
            int arow = grp * 16 + l15;
            int aslot = (ks * 4 + lg) ^ (arow & 7);
            bf16x8 af = *(const bf16x8*)((char*)xb + arow * 256 + aslot * 16);
#pragma unroll
            for (int ntl = 0; ntl < 4; ++ntl) {
                int brow = (half * 4 + ntl) * 16 + l15;
                int bslot = (ks * 4 + lg) ^ (brow & 7);
                bf16x8 bfr = *(bf16x8*)((char*)w1b + brow * 256 + bslot * 16);
                acc1[ntl] = __builtin_amdgcn_mfma_f32_16x16x32_bf16(af, bfr, acc1[ntl], 0, 0, 0);
            }
        }
        __syncthreads();   // A: all xb A-reads done before h overwrites xb
        // ---- cheap tanh -> myhb: tanh(a) = 1 - 2*rcp(e^{2a}+1), saturation-safe ----
#pragma unroll
        for (int ntl = 0; ntl < 4; ++ntl)
#pragma unroll
            for (int r = 0; r < 4; ++r) {
                float aa = acc1[ntl][r];
                float e2 = __expf(2.f * aa);                       // inf for large aa: ok
                float th = fmaf(-2.f, __builtin_amdgcn_rcpf(e2 + 1.f), 1.f);
                int m = lg * 4 + r;
                int np = ntl * 16 + l15;
                int slot = ((np >> 3) + m) & 7;
                *(unsigned short*)(myhb + m * 128 + slot * 16 + (np & 7) * 2) = f2b_up(th);
            }
        // ---- GEMM2 (own k-half): A row m = l15, k-slot = kk*4+lg ----
        f32x4 acc2;
#pragma unroll
        for (int r = 0; r < 4; ++r) acc2[r] = 0.f;
#pragma unroll
        for (int kk = 0; kk < 2; ++kk) {
            int slot = ((kk * 4 + lg) + l15) & 7;
            bf16x8 hf = *(bf16x8*)(myhb + l15 * 128 + slot * 16);
            acc2 = __builtin_amdgcn_mfma_f32_16x16x32_bf16(hf, w2f[kk], acc2, 0, 0, 0);
        }
        if (half) pb[grp][lane] = acc2;
        __syncthreads();   // B: partials visible; all h reads done
        if (!half) {
            f32x4 po = pb[grp][lane];
#pragma unroll
            for (int r = 0; r < 4; ++r) acc2[r] += po[r];
            if (l15 < 8) {
#pragma unroll
                for (int r = 0; r < 4; ++r) {
                    int node = base + grp * 16 + lg * 4 + r;
                    if (node < n_nodes) scores[node * 8 + l15] = acc2[r];
                }
            }
        }
        // ---- stage next tile (overwrites xb/h: safe after barrier B) ----
        {
            int nxt = tile + gridDim.x;
            if (nxt < ntile) {
#pragma unroll
                for (int i = 0; i < 4; ++i) {
                    int f4 = i * 512 + t;
                    int row = f4 >> 5, q = f4 & 31;
                    int node = nxt * 64 + row; if (node >= n_nodes) node = n_nodes - 1;
                    float4 v = ((const float4*)x)[(size_t)node * 32 + q];
                    ushort4 p;
                    p.x = f2b(v.x); p.y = f2b(v.y); p.z = f2b(v.z); p.w = f2b(v.w);
                    int slot = (q >> 1) ^ (row & 7);
                    *(ushort4*)((char*)xb + row * 256 + slot * 16 + (q & 1) * 8) = p;
                }
            }
        }
        __syncthreads();   // C: next xb ready
    }
}

// ---------------- Phase B+C: per-graph bounds (binary search) + stats (in-reg)
//                  + staged PV. One block per graph; 2 dispatches total. ----------------
__global__ __launch_bounds__(256) void out_kernel(
    const float* __restrict__ x, const float* __restrict__ scores,
    const int* __restrict__ batch, float* __restrict__ out, int n_nodes)
{
    __shared__ float redm[256], redl[256];
    __shared__ __align__(16) float xsl[16 * 128];
    __shared__ __align__(16) float atl[16 * 8];
    __shared__ int sse[2];
    const int g = blockIdx.x, t = threadIdx.x;
    const int lane = t & 63;

    // ---- segment bounds: lower_bound(batch, g) and (batch, g+1) ----
    if (t < 2) {
        int v = g + t;
        int lo = 0, hi = n_nodes;
        while (lo < hi) { int mid = (lo + hi) >> 1; if (batch[mid] < v) lo = mid + 1; else hi = mid; }
        sse[t] = lo;
    }
    __syncthreads();
    const int s = sse[0];
    const int e = sse[1];
    float* og = out + (size_t)g * 1024;
    const int f = t & 127, ob = t >> 7;
    if (e <= s) {     // empty graph: segment_sum identity = 0 (block-uniform exit)
        og[ob * 512 + f] = 0.f; og[ob * 512 + 128 + f] = 0.f;
        og[ob * 512 + 256 + f] = 0.f; og[ob * 512 + 384 + f] = 0.f;
        return;
    }
    const int o = t & 7, j0 = t >> 3;

    // ---- pass 1: graph max per head (shfl-reduced; every thread gets M for o=t&7) ----
    float m = -INFINITY;
    for (int n = s + j0; n < e; n += 32) m = fmaxf(m, scores[n * 8 + o]);
    redm[t] = m;
    __syncthreads();
    float M = fmaxf(fmaxf(redm[lane], redm[lane + 64]), fmaxf(redm[lane + 128], redm[lane + 192]));
    M = fmaxf(M, __shfl_xor(M, 8));
    M = fmaxf(M, __shfl_xor(M, 16));
    M = fmaxf(M, __shfl_xor(M, 32));
    // ---- pass 2: denom per head ----
    float l = 0.f;
    for (int n = s + j0; n < e; n += 32) l += __expf(scores[n * 8 + o] - M);
    redl[t] = l;
    __syncthreads();
    float L = (redl[lane] + redl[lane + 64]) + (redl[lane + 128] + redl[lane + 192]);
    L += __shfl_xor(L, 8);
    L += __shfl_xor(L, 16);
    L += __shfl_xor(L, 32);
    const float gi = 1.f / L;

    // ---- PV: 16-node chunks, xsl + atl staged ----
    float a0 = 0.f, a1 = 0.f, a2 = 0.f, a3 = 0.f;
    for (int c = s; c < e; c += 16) {
        const int cnt = min(16, e - c);
        __syncthreads();   // protects prev-iter reads (first iter: redm/redl done)
#pragma unroll
        for (int i = 0; i < 2; ++i) {
            int f4 = i * 256 + t;
            int row = f4 >> 5, col4 = f4 & 31;
            if (row < cnt)
                ((float4*)xsl)[row * 32 + col4] = ((const float4*)x)[(size_t)(c + row) * 32 + col4];
        }
        if (t < 128) {
            int j = t >> 3;
            if (j < cnt)
                atl[j * 8 + o] = __expf(scores[(c + j) * 8 + o] - M) * gi;
        }
        __syncthreads();
        for (int j = 0; j < cnt; ++j) {
            float xv = xsl[j * 128 + f];
            float4 a4 = ((const float4*)atl)[j * 2 + ob];
            a0 = fmaf(a4.x, xv, a0); a1 = fmaf(a4.y, xv, a1);
            a2 = fmaf(a4.z, xv, a2); a3 = fmaf(a4.w, xv, a3);
        }
    }
    const int gb = ob * 512 + f;
    og[gb]       = a0;
    og[gb + 128] = a1;
    og[gb + 256] = a2;
    og[gb + 384] = a3;
}

extern "C" void kernel_launch(void* const* d_in, const int* in_sizes, int n_in,
                              void* d_out, int out_size, void* d_ws, size_t ws_size,
                              hipStream_t stream)
{
    const float* x     = (const float*)d_in[0];
    const int*   batch = (const int*)d_in[1];
    const float* w1    = (const float*)d_in[2];
    const float* w2    = (const float*)d_in[3];
    const int n_nodes  = in_sizes[1];
    float* out = (float*)d_out;

    float* scores = (float*)d_ws;   // n*8 floats

    const int ntile = (n_nodes + 63) / 64;
    hipLaunchKernelGGL(score_kernel, dim3(768), dim3(512), 0, stream, x, w1, w2, scores, n_nodes, ntile);
    hipLaunchKernelGGL(out_kernel,   dim3(GG),  dim3(256), 0, stream, x, scores, batch, out, n_nodes);
}